// Round 6
// baseline (78.804 us; speedup 1.0000x reference)
//
#include <hip/hip_runtime.h>
#include <hip/hip_bf16.h>

#define NSUB 16
#define MM 20
#define NFILT 2000
#define TRI (MM*(MM+1)/2)
#define WR 1000          // output rows per block (half window)

// params published by setup kernel, consumed by main kernel (same-stream ordering)
__device__ __align__(16) float g_mu[32];
__device__ __align__(16) float g_W[16];
__device__ __align__(16) float g_Th[16];
__device__ float g_Vo;

__device__ __forceinline__ float ftanh(float x) {
  x = fminf(10.f, fmaxf(-10.f, x));
  float e = __expf(2.f * x);
  return (e - 1.f) * __builtin_amdgcn_rcpf(e + 1.f);
}

// uniform value -> SGPR
__device__ __forceinline__ float rfl(float v) {
  return __int_as_float(__builtin_amdgcn_readfirstlane(__float_as_int(v)));
}

__device__ __forceinline__ float f4c(const float4& v, int c) {
  return c == 0 ? v.x : c == 1 ? v.y : c == 2 ? v.z : v.w;
}

// full wave64 inclusive add-scan, pure VALU DPP (HW-validated R2)
__device__ __forceinline__ float wave_incl_scan(float x) {
  float t;
  t = __int_as_float(__builtin_amdgcn_update_dpp(0, __float_as_int(x), 0x111, 0xf, 0xf, true)); x += t;
  t = __int_as_float(__builtin_amdgcn_update_dpp(0, __float_as_int(x), 0x112, 0xf, 0xf, true)); x += t;
  t = __int_as_float(__builtin_amdgcn_update_dpp(0, __float_as_int(x), 0x114, 0xf, 0xf, true)); x += t;
  t = __int_as_float(__builtin_amdgcn_update_dpp(0, __float_as_int(x), 0x118, 0xf, 0xf, true)); x += t;
  t = __int_as_float(__builtin_amdgcn_update_dpp(0, __float_as_int(x), 0x142, 0xa, 0xf, true)); x += t; // bcast15 -> rows 1,3
  t = __int_as_float(__builtin_amdgcn_update_dpp(0, __float_as_int(x), 0x143, 0xc, 0xf, true)); x += t; // bcast31 -> rows 2,3
  return x;
}

#define UNPACK2(u, o0, o1) { union {unsigned int q; float f;} a_, b_; \
  a_.q = (u) << 16; b_.q = (u) & 0xffff0000u; (o0) = a_.f; (o1) = b_.f; }
#define U16(h) ((unsigned int)*(unsigned short*)&(h))

// ---------------------------------------------------------------------------
// Setup: one 64-thread block per subunit; register-column Gauss-Jordan
// (lane j owns column j of [cov | I]); f32 only.
// ---------------------------------------------------------------------------
__global__ void __launch_bounds__(64)
k_setup(const float* alpha_log, const float* beta_p, const float* gamma_log,
        const float* kvlog, const float* mean_u, const float* su_low,
        const float* u_in, const float* W_log, const float* V_o_p,
        const float* Theta, float* out, int T)
{
  const int s = blockIdx.x;       // 0..31
  const int lane = threadIdx.x;   // 0..63

  const float alpha = __expf(alpha_log[s]);
  const float beta  = beta_p[s];
  const float gamma = __expf(gamma_log[s]);
  const float kv    = __expf(kvlog[s]);
  const float fs    = (float)s;

  const long long OFF_MEANU = T;
  const long long OFF_SU    = (long long)T + 640;
  const long long OFF_COV   = (long long)T + 640 + 12800;
  const long long OFF_INV   = (long long)T + 640 + 2*12800;
  const long long OFF_FE    = (long long)T + 640 + 3*12800;
  const long long OFF_FI    = OFF_FE + 32000;
  const long long OFF_UIN   = OFF_FI + 32000;

  float urv[MM], t1v[MM], rv_[MM];
#pragma unroll
  for (int i = 0; i < MM; ++i) {
    float u = u_in[s*MM + i];
    urv[i] = u;
    t1v[i] = alpha * (u - beta) * (u - beta);
    rv_[i] = kv * __expf(-alpha*(fs-beta)*(fs-beta) - gamma*(fs-u)*(fs-u) - t1v[i]);
  }

  const bool cL = lane < MM;
  const bool cR = lane >= MM && lane < 2*MM;
  const float u_l = u_in[s*MM + (cL ? lane : 0)];
  const float t1_l = alpha * (u_l - beta) * (u_l - beta);

  float col[MM];
#pragma unroll
  for (int i = 0; i < MM; ++i) {
    float du = urv[i] - u_l;
    float cv = kv * __expf(-t1v[i] - gamma*du*du - t1_l);
    float idv = (lane - MM == i) ? 1.f : 0.f;
    col[i] = cL ? cv : (cR ? idv : 0.f);
    if (cL) out[OFF_COV + (long long)s*400 + i*MM + lane] = cv;
  }

#pragma unroll
  for (int k = 0; k < MM; ++k) {
    float fc[MM];
#pragma unroll
    for (int i = 0; i < MM; ++i)
      fc[i] = __int_as_float(__builtin_amdgcn_readlane(__float_as_int(col[i]), k));
    const float pr = 1.0f / fc[k];
    col[k] *= pr;
#pragma unroll
    for (int i = 0; i < MM; ++i)
      if (i != k) col[i] = fmaf(-fc[i], col[k], col[i]);
  }

  if (cR) {
    const int t = lane - MM;
#pragma unroll
    for (int i = 0; i < MM; ++i)
      out[OFF_INV + (long long)s*400 + i*MM + t] = col[i];
  }

  float dotr = 0.f;
#pragma unroll
  for (int i = 0; i < MM; ++i) dotr += rv_[i] * col[i];
  float mpart = cR ? dotr * mean_u[s*MM + (lane - MM)] : 0.f;
  float mu = mpart;
#pragma unroll
  for (int o = 1; o < 64; o <<= 1) mu += __shfl_xor(mu, o, 64);
  mu = rfl(mu);
  if (lane == 0) g_mu[s] = mu;

  __shared__ float Lm[MM][MM];
  for (int c = lane; c < MM*MM; c += 64) Lm[c/MM][c%MM] = 0.f;
  __syncthreads();
  for (int k = lane; k < TRI; k += 64) {
    int i = (int)((sqrtf(8.f*(float)k + 1.f) - 1.f) * 0.5f);
    while ((i+1)*(i+2)/2 <= k) ++i;
    while (i*(i+1)/2 > k) --i;
    int jx = k - i*(i+1)/2;
    Lm[i][jx] = su_low[s*TRI + k];
  }
  __syncthreads();
  for (int c = lane; c < MM*MM; c += 64) {
    int i = c / MM, kk = c % MM;
    float acc = 0.f;
#pragma unroll
    for (int jx = 0; jx < MM; ++jx) acc += Lm[i][jx] * Lm[kk][jx];
    out[OFF_SU + (long long)s*400 + c] = acc;
  }

  if (cL) {
    out[OFF_MEANU + s*MM + lane] = mean_u[s*MM + lane];
    out[OFF_UIN  + s*MM + lane] = u_l;
  }

  {
    long long base = (s < NSUB) ? (OFF_FE + (long long)s*NFILT)
                                : (OFF_FI + (long long)(s - NSUB)*NFILT);
    float2 f2 = make_float2(mu, mu);
    float2* dst = (float2*)(out + base);
    for (int n = lane; n < NFILT/2; n += 64) dst[n] = f2;
  }

  if (s == 0) {
    if (lane < 16) {
      g_W[lane]  = __expf(W_log[lane]);
      g_Th[lane] = Theta[lane];
    }
    if (lane == 0) g_Vo = V_o_p[0];
  }
}

// ---------------------------------------------------------------------------
// Main: 500 blocks x 512 threads; block b outputs rows [1000b, 1000b+1000).
// syn[t] = Base + prefix(diff[s..t]),  diff[u] = m[u] - m[u-2000],
// Base = sum m over [s-2000, s)  (lag rows shared with diff; extra rows
// [s-1000,s) read once more -> 3000 rows/block, extra absorbed by L2/L3).
// Phase A: depth-2 x 6-stream float4 pipeline, fma, bf16 diffs -> 32KB LDS
// tile (uniform bank-pairs). Zero cross-lane ops in the loop.
// Phase B: per-col 64-lane DPP scan + 8-wave base table; 2 tanh chains/lane.
// ---------------------------------------------------------------------------
__global__ void __launch_bounds__(512, 4)
k_main(const float* S_e, const float* S_i, float* out, int T)
{
  __shared__ __align__(16) unsigned int tile[1024*8];  // [1024 rows][8 u32] bf16
  __shared__ float baseTot[8][16];
  __shared__ float wdTot[8][16];
  __shared__ float bsv[8][16];

  const int tid  = threadIdx.x;    // 0..511
  const int lane = tid & 63;
  const int w    = tid >> 6;       // 0..7
  const int g    = tid & 3;        // quarter (4 cols)
  const int rr   = tid >> 2;       // 0..127 row-in-sweep

  const int s_row = blockIdx.x * WR;
  const float4* E4 = (const float4*)S_e;
  const float4* I4 = (const float4*)S_i;

  const float4 mue4 = *(const float4*)&g_mu[4*g];
  const float4 mui4 = *(const float4*)&g_mu[16 + 4*g];

  float baseAcc[4] = {0.f, 0.f, 0.f, 0.f};
  float dTot[4]    = {0.f, 0.f, 0.f, 0.f};

  float4 ce[2], ciw[2], le[2], liw[2], xe[2], xiw[2];
  const float4 z4 = make_float4(0.f, 0.f, 0.f, 0.f);

#define LOADS(SL, SW) { \
    const int lr = 128*(SW) + rr; \
    const int gc = s_row + lr; \
    const int gl = gc - NFILT; \
    const int ge = s_row - WR + lr; \
    const bool vc = (lr < WR) && (gc < T); \
    const bool vl = vc && (gl >= 0); \
    const bool vx = (lr < WR) && (ge >= 0) && (ge < T); \
    const int ic = gc*4 + g, il = gl*4 + g, ix = ge*4 + g; \
    ce[SL]  = vc ? E4[ic] : z4;  ciw[SL] = vc ? I4[ic] : z4; \
    le[SL]  = vl ? E4[il] : z4;  liw[SL] = vl ? I4[il] : z4; \
    xe[SL]  = vx ? E4[ix] : z4;  xiw[SL] = vx ? I4[ix] : z4; \
  }

#define CONS(SL, SW) { \
    const int lr = 128*(SW) + rr; \
    float dp[4]; \
    _Pragma("unroll") \
    for (int c = 0; c < 4; ++c) { \
      const float mu_e = f4c(mue4, c), mu_i = f4c(mui4, c); \
      const float mc = mu_e*f4c(ce[SL], c) + mu_i*f4c(ciw[SL], c); \
      const float ml = mu_e*f4c(le[SL], c) + mu_i*f4c(liw[SL], c); \
      const float mx = mu_e*f4c(xe[SL], c) + mu_i*f4c(xiw[SL], c); \
      baseAcc[c] += ml + mx; \
      dp[c] = mc - ml; \
      dTot[c] += dp[c]; \
    } \
    __hip_bfloat16 h0 = __float2bfloat16(dp[0]), h1 = __float2bfloat16(dp[1]); \
    __hip_bfloat16 h2 = __float2bfloat16(dp[2]), h3 = __float2bfloat16(dp[3]); \
    uint2 pk; \
    pk.x = U16(h0) | (U16(h1) << 16); \
    pk.y = U16(h2) | (U16(h3) << 16); \
    *(uint2*)((unsigned char*)tile + lr*32 + g*8) = pk; \
  }

  LOADS(0, 0)
#pragma unroll
  for (int sw = 0; sw < 8; ++sw) {
    if (sw < 7) LOADS((sw + 1) & 1, sw + 1)
    CONS(sw & 1, sw)
  }
#undef LOADS
#undef CONS

  // reduce base/diff totals across the 16 rows sharing each quarter
#pragma unroll
  for (int c = 0; c < 4; ++c) {
#pragma unroll
    for (int o = 4; o <= 32; o <<= 1) {
      baseAcc[c] += __shfl_xor(baseAcc[c], o, 64);
      dTot[c]    += __shfl_xor(dTot[c],    o, 64);
    }
  }
  if (lane < 4) {   // lane == its quarter g; holds cols 4g..4g+3
    *(float4*)&baseTot[w][4*lane] = make_float4(baseAcc[0], baseAcc[1], baseAcc[2], baseAcc[3]);
    *(float4*)&wdTot[w][4*lane]   = make_float4(dTot[0], dTot[1], dTot[2], dTot[3]);
  }
  __syncthreads();

  // wave 0: bsv[wt][c] = Th[c] + sum_all baseTot + sum_{w'<wt} wdTot
  if (w == 0) {
    const int wt = lane & 7, cp = lane >> 3;   // cols 2cp, 2cp+1
    float b0 = 0.f, b1 = 0.f, e0 = 0.f, e1 = 0.f;
#pragma unroll
    for (int wp = 0; wp < 8; ++wp) {
      float2 bt = *(const float2*)&baseTot[wp][2*cp];
      float2 dt = *(const float2*)&wdTot[wp][2*cp];
      b0 += bt.x; b1 += bt.y;
      const bool pz = (wp < wt);
      e0 += pz ? dt.x : 0.f;
      e1 += pz ? dt.y : 0.f;
    }
    const float2 th = *(const float2*)&g_Th[2*cp];
    *(float2*)&bsv[wt][2*cp] = make_float2(th.x + b0 + e0, th.y + b1 + e1);
  }
  __syncthreads();

  // ---------------- phase B ----------------
  const bool act = tid < WR/2;   // 500 active threads, rows 2t, 2t+1
  float d0[16], d1[16];
  if (act) {
    const unsigned char* base = (const unsigned char*)tile + 64*tid;
    uint4 a0 = *(const uint4*)(base);
    uint4 a1 = *(const uint4*)(base + 16);
    uint4 b0 = *(const uint4*)(base + 32);
    uint4 b1 = *(const uint4*)(base + 48);
    UNPACK2(a0.x, d0[0], d0[1])   UNPACK2(a0.y, d0[2], d0[3])
    UNPACK2(a0.z, d0[4], d0[5])   UNPACK2(a0.w, d0[6], d0[7])
    UNPACK2(a1.x, d0[8], d0[9])   UNPACK2(a1.y, d0[10], d0[11])
    UNPACK2(a1.z, d0[12], d0[13]) UNPACK2(a1.w, d0[14], d0[15])
    UNPACK2(b0.x, d1[0], d1[1])   UNPACK2(b0.y, d1[2], d1[3])
    UNPACK2(b0.z, d1[4], d1[5])   UNPACK2(b0.w, d1[6], d1[7])
    UNPACK2(b1.x, d1[8], d1[9])   UNPACK2(b1.y, d1[10], d1[11])
    UNPACK2(b1.z, d1[12], d1[13]) UNPACK2(b1.w, d1[14], d1[15])
  } else {
#pragma unroll
    for (int c = 0; c < 16; ++c) { d0[c] = 0.f; d1[c] = 0.f; }
  }

  float ex[16];
#pragma unroll
  for (int c = 0; c < 16; ++c) {
    const float x = d0[c] + d1[c];
    const float inc = wave_incl_scan(x);
    ex[c] = inc - x;
  }

  float bs[16];
#pragma unroll
  for (int q = 0; q < 4; ++q) {
    float4 t4 = *(const float4*)&bsv[w][4*q];
    bs[4*q] = t4.x; bs[4*q+1] = t4.y; bs[4*q+2] = t4.z; bs[4*q+3] = t4.w;
  }
  float wk[16];
#pragma unroll
  for (int k = 0; k < 16; ++k) wk[k] = rfl(g_W[k]);
  const float Vo = rfl(g_Vo);

  float W0v[16], W1v[16];
#pragma unroll
  for (int c = 0; c < 16; ++c) {
    W0v[c] = bs[c] + ex[c] + d0[c];
    W1v[c] = W0v[c] + d1[c];
  }
  float v0 = ftanh(W0v[15]);
  float v1 = ftanh(W1v[15]);
#pragma unroll
  for (int idx = 14; idx >= 0; --idx) {
    const float wkk = wk[idx + 1];
    v0 = ftanh(W0v[idx] + wkk * v0);
    v1 = ftanh(W1v[idx] + wkk * v1);
  }
  const float o0 = v0 * wk[0] + Vo;
  const float o1 = v1 * wk[0] + Vo;

  if (act) {
    const long long gr = (long long)s_row + 2*tid;
    if (gr + 1 < T) {
      *(float2*)(out + gr) = make_float2(o0, o1);
    } else if (gr < T) {
      out[gr] = o0;
    }
  }
}

extern "C" void kernel_launch(void* const* d_in, const int* in_sizes, int n_in,
                              void* d_out, int out_size, void* d_ws, size_t ws_size,
                              hipStream_t stream) {
  const float* S_e       = (const float*)d_in[0];
  const float* S_i       = (const float*)d_in[1];
  const float* alpha_log = (const float*)d_in[2];
  const float* beta      = (const float*)d_in[3];
  const float* gamma_log = (const float*)d_in[4];
  const float* kvlog     = (const float*)d_in[5];
  const float* mean_u    = (const float*)d_in[6];
  const float* su_low    = (const float*)d_in[7];
  const float* u_in      = (const float*)d_in[8];
  const float* W_log     = (const float*)d_in[9];
  const float* V_o       = (const float*)d_in[10];
  const float* Theta     = (const float*)d_in[11];
  (void)d_ws; (void)ws_size; (void)n_in; (void)out_size;

  const int T = in_sizes[0] / NSUB;
  const int nb = (T + WR - 1) / WR;

  hipLaunchKernelGGL(k_setup, dim3(32), dim3(64), 0, stream,
                     alpha_log, beta, gamma_log, kvlog, mean_u, su_low, u_in,
                     W_log, V_o, Theta, (float*)d_out, T);
  hipLaunchKernelGGL(k_main, dim3(nb), dim3(512), 0, stream,
                     S_e, S_i, (float*)d_out, T);
}

// Round 7
// 68.895 us; speedup vs baseline: 1.1438x; 1.1438x over previous
//
#include <hip/hip_runtime.h>
#include <hip/hip_fp16.h>

#define NSUB 16
#define MM 20
#define NFILT 2000
#define TRI (MM*(MM+1)/2)
#define WR 1000          // output rows per k_out block
#define GRP 250          // rows per k_fold block / G group

// params published by setup kernel, consumed by later kernels (same-stream order)
__device__ __align__(16) float g_mu[32];
__device__ __align__(16) float g_W[16];
__device__ __align__(16) float g_Th[16];
__device__ float g_Vo;

__device__ __forceinline__ float ftanh(float x) {
  x = fminf(10.f, fmaxf(-10.f, x));
  float e = __expf(2.f * x);
  return (e - 1.f) * __builtin_amdgcn_rcpf(e + 1.f);
}

// uniform value -> SGPR
__device__ __forceinline__ float rfl(float v) {
  return __int_as_float(__builtin_amdgcn_readfirstlane(__float_as_int(v)));
}

__device__ __forceinline__ float f4c(const float4& v, int c) {
  return c == 0 ? v.x : c == 1 ? v.y : c == 2 ? v.z : v.w;
}

// full wave64 inclusive add-scan, pure VALU DPP (HW-validated R2)
__device__ __forceinline__ float wave_incl_scan(float x) {
  float t;
  t = __int_as_float(__builtin_amdgcn_update_dpp(0, __float_as_int(x), 0x111, 0xf, 0xf, true)); x += t;
  t = __int_as_float(__builtin_amdgcn_update_dpp(0, __float_as_int(x), 0x112, 0xf, 0xf, true)); x += t;
  t = __int_as_float(__builtin_amdgcn_update_dpp(0, __float_as_int(x), 0x114, 0xf, 0xf, true)); x += t;
  t = __int_as_float(__builtin_amdgcn_update_dpp(0, __float_as_int(x), 0x118, 0xf, 0xf, true)); x += t;
  t = __int_as_float(__builtin_amdgcn_update_dpp(0, __float_as_int(x), 0x142, 0xa, 0xf, true)); x += t; // bcast15 -> rows 1,3
  t = __int_as_float(__builtin_amdgcn_update_dpp(0, __float_as_int(x), 0x143, 0xc, 0xf, true)); x += t; // bcast31 -> rows 2,3
  return x;
}

// f16x2 helpers
__device__ __forceinline__ unsigned int f2h2(float a, float b) {
  __half2 h = __floats2half2_rn(a, b);
  union { __half2 h; unsigned int u; } cv; cv.h = h; return cv.u;
}
__device__ __forceinline__ float2 h2f2(unsigned int u) {
  union { unsigned int u; __half2 h; } cv; cv.u = u;
  return __half22float2(cv.h);
}
__device__ __forceinline__ void sub2(unsigned int cu, unsigned int lg, float& o0, float& o1) {
  float2 a = h2f2(cu), b = h2f2(lg);
  o0 = a.x - b.x; o1 = a.y - b.y;
}

// ---------------------------------------------------------------------------
// Setup: one 64-thread block per subunit; register-column Gauss-Jordan
// (lane j owns column j of [cov | I]); f32 only. (Validated R5/R6.)
// ---------------------------------------------------------------------------
__global__ void __launch_bounds__(64)
k_setup(const float* alpha_log, const float* beta_p, const float* gamma_log,
        const float* kvlog, const float* mean_u, const float* su_low,
        const float* u_in, const float* W_log, const float* V_o_p,
        const float* Theta, float* out, int T)
{
  const int s = blockIdx.x;       // 0..31
  const int lane = threadIdx.x;   // 0..63

  const float alpha = __expf(alpha_log[s]);
  const float beta  = beta_p[s];
  const float gamma = __expf(gamma_log[s]);
  const float kv    = __expf(kvlog[s]);
  const float fs    = (float)s;

  const long long OFF_MEANU = T;
  const long long OFF_SU    = (long long)T + 640;
  const long long OFF_COV   = (long long)T + 640 + 12800;
  const long long OFF_INV   = (long long)T + 640 + 2*12800;
  const long long OFF_FE    = (long long)T + 640 + 3*12800;
  const long long OFF_FI    = OFF_FE + 32000;
  const long long OFF_UIN   = OFF_FI + 32000;

  float urv[MM], t1v[MM], rv_[MM];
#pragma unroll
  for (int i = 0; i < MM; ++i) {
    float u = u_in[s*MM + i];
    urv[i] = u;
    t1v[i] = alpha * (u - beta) * (u - beta);
    rv_[i] = kv * __expf(-alpha*(fs-beta)*(fs-beta) - gamma*(fs-u)*(fs-u) - t1v[i]);
  }

  const bool cL = lane < MM;
  const bool cR = lane >= MM && lane < 2*MM;
  const float u_l = u_in[s*MM + (cL ? lane : 0)];
  const float t1_l = alpha * (u_l - beta) * (u_l - beta);

  float col[MM];
#pragma unroll
  for (int i = 0; i < MM; ++i) {
    float du = urv[i] - u_l;
    float cv = kv * __expf(-t1v[i] - gamma*du*du - t1_l);
    float idv = (lane - MM == i) ? 1.f : 0.f;
    col[i] = cL ? cv : (cR ? idv : 0.f);
    if (cL) out[OFF_COV + (long long)s*400 + i*MM + lane] = cv;
  }

#pragma unroll
  for (int k = 0; k < MM; ++k) {
    float fc[MM];
#pragma unroll
    for (int i = 0; i < MM; ++i)
      fc[i] = __int_as_float(__builtin_amdgcn_readlane(__float_as_int(col[i]), k));
    const float pr = 1.0f / fc[k];
    col[k] *= pr;
#pragma unroll
    for (int i = 0; i < MM; ++i)
      if (i != k) col[i] = fmaf(-fc[i], col[k], col[i]);
  }

  if (cR) {
    const int t = lane - MM;
#pragma unroll
    for (int i = 0; i < MM; ++i)
      out[OFF_INV + (long long)s*400 + i*MM + t] = col[i];
  }

  float dotr = 0.f;
#pragma unroll
  for (int i = 0; i < MM; ++i) dotr += rv_[i] * col[i];
  float mpart = cR ? dotr * mean_u[s*MM + (lane - MM)] : 0.f;
  float mu = mpart;
#pragma unroll
  for (int o = 1; o < 64; o <<= 1) mu += __shfl_xor(mu, o, 64);
  mu = rfl(mu);
  if (lane == 0) g_mu[s] = mu;

  __shared__ float Lm[MM][MM];
  for (int c = lane; c < MM*MM; c += 64) Lm[c/MM][c%MM] = 0.f;
  __syncthreads();
  for (int k = lane; k < TRI; k += 64) {
    int i = (int)((sqrtf(8.f*(float)k + 1.f) - 1.f) * 0.5f);
    while ((i+1)*(i+2)/2 <= k) ++i;
    while (i*(i+1)/2 > k) --i;
    int jx = k - i*(i+1)/2;
    Lm[i][jx] = su_low[s*TRI + k];
  }
  __syncthreads();
  for (int c = lane; c < MM*MM; c += 64) {
    int i = c / MM, kk = c % MM;
    float acc = 0.f;
#pragma unroll
    for (int jx = 0; jx < MM; ++jx) acc += Lm[i][jx] * Lm[kk][jx];
    out[OFF_SU + (long long)s*400 + c] = acc;
  }

  if (cL) {
    out[OFF_MEANU + s*MM + lane] = mean_u[s*MM + lane];
    out[OFF_UIN  + s*MM + lane] = u_l;
  }

  {
    long long base = (s < NSUB) ? (OFF_FE + (long long)s*NFILT)
                                : (OFF_FI + (long long)(s - NSUB)*NFILT);
    float2 f2 = make_float2(mu, mu);
    float2* dst = (float2*)(out + base);
    for (int n = lane; n < NFILT/2; n += 64) dst[n] = f2;
  }

  if (s == 0) {
    if (lane < 16) {
      g_W[lane]  = __expf(W_log[lane]);
      g_Th[lane] = Theta[lane];
    }
    if (lane == 0) g_Vo = V_o_p[0];
  }
}

// ---------------------------------------------------------------------------
// k_fold: pure stream. Block a covers rows [250a, 250a+250).
// Thread = one half-row (8 channels): 4 coalesced float4 loads, 8 fma,
// f16x8 pack -> one uint4 store to M. Per-block G[a][16] channel sums via
// a single parity shfl reduce + tiny LDS (once per block, not in a loop).
// ---------------------------------------------------------------------------
__global__ void __launch_bounds__(512, 4)
k_fold(const float* __restrict__ S_e, const float* __restrict__ S_i,
       uint4* __restrict__ M4, float* __restrict__ G, int T)
{
  __shared__ float wsum[8][16];
  const int tid  = threadIdx.x;    // 0..511
  const int lane = tid & 63;
  const int w    = tid >> 6;       // 0..7
  const int a    = blockIdx.x;
  const int row  = a*GRP + (tid >> 1);
  const int hf   = tid & 1;        // half of row: channels 8hf..8hf+7
  const bool act = (tid < 2*GRP) && (row < T);

  const float4* E4 = (const float4*)S_e;
  const float4* I4 = (const float4*)S_i;
  const float4 z4 = make_float4(0.f, 0.f, 0.f, 0.f);
  const int fi = row*4 + 2*hf;
  float4 e0 = act ? E4[fi]   : z4;
  float4 e1 = act ? E4[fi+1] : z4;
  float4 i0 = act ? I4[fi]   : z4;
  float4 i1 = act ? I4[fi+1] : z4;

  const float4 muea = *(const float4*)&g_mu[8*hf];
  const float4 mueb = *(const float4*)&g_mu[8*hf + 4];
  const float4 muia = *(const float4*)&g_mu[16 + 8*hf];
  const float4 muib = *(const float4*)&g_mu[16 + 8*hf + 4];

  float m[8];
#pragma unroll
  for (int j = 0; j < 4; ++j) m[j]     = f4c(muea,j)*f4c(e0,j) + f4c(muia,j)*f4c(i0,j);
#pragma unroll
  for (int j = 0; j < 4; ++j) m[4 + j] = f4c(mueb,j)*f4c(e1,j) + f4c(muib,j)*f4c(i1,j);

  if (act) {
    uint4 pk;
    pk.x = f2h2(m[0], m[1]);
    pk.y = f2h2(m[2], m[3]);
    pk.z = f2h2(m[4], m[5]);
    pk.w = f2h2(m[6], m[7]);
    M4[(long long)row*2 + hf] = pk;
  }

  // per-block channel sums: even lanes hold c0-7, odd lanes c8-15
#pragma unroll
  for (int j = 0; j < 8; ++j) {
#pragma unroll
    for (int o = 2; o <= 32; o <<= 1) m[j] += __shfl_xor(m[j], o, 64);
  }
  if (lane < 2) {
#pragma unroll
    for (int j = 0; j < 8; ++j) wsum[w][8*lane + j] = m[j];
  }
  __syncthreads();
  if (tid < 16) {
    float acc = 0.f;
#pragma unroll
    for (int wp = 0; wp < 8; ++wp) acc += wsum[wp][tid];
    G[a*16 + tid] = acc;
  }
}

// ---------------------------------------------------------------------------
// k_out: block b outputs rows [1000b, 1000b+1000).
// W[t] = Th + sum(G over [s-2000,s)) + prefix(M[s..t]) - prefix(M[s-2000..t-2000]).
// Thread: 2 cur rows + 2 lag rows of M (8 uint4 coalesced loads, L2/L3-hot),
// per-channel DPP scan + wave0 base table, 2 tanh chains, float2 store.
// ---------------------------------------------------------------------------
__global__ void __launch_bounds__(512, 4)
k_out(const uint4* __restrict__ M4, const float* __restrict__ G,
      float* __restrict__ out, int T)
{
  __shared__ float wdTot[8][16];
  __shared__ float bsv[8][16];
  const int tid  = threadIdx.x;    // 0..511
  const int lane = tid & 63;
  const int w    = tid >> 6;
  const int b    = blockIdx.x;
  const long long s  = (long long)b * WR;
  const long long r0 = s + 2*tid;            // even
  const bool a0 = (tid < WR/2) && (r0 < T);
  const bool a1 = a0 && (r0 + 1 < T);
  const long long l0 = r0 - 2*NFILT/2;       // r0 - 2000 (even)
  const bool v0 = a0 && (l0 >= 0);
  const bool v1 = a1 && (l0 >= 0);

  const uint4 zu = make_uint4(0u, 0u, 0u, 0u);
  uint4 c0 = a0 ? M4[r0*2]     : zu;
  uint4 c1 = a0 ? M4[r0*2 + 1] : zu;
  uint4 c2 = a1 ? M4[r0*2 + 2] : zu;
  uint4 c3 = a1 ? M4[r0*2 + 3] : zu;
  uint4 g0 = v0 ? M4[l0*2]     : zu;
  uint4 g1 = v0 ? M4[l0*2 + 1] : zu;
  uint4 g2 = v1 ? M4[l0*2 + 2] : zu;
  uint4 g3 = v1 ? M4[l0*2 + 3] : zu;

  float d0[16], d1[16];
  sub2(c0.x, g0.x, d0[0],  d0[1]);  sub2(c0.y, g0.y, d0[2],  d0[3]);
  sub2(c0.z, g0.z, d0[4],  d0[5]);  sub2(c0.w, g0.w, d0[6],  d0[7]);
  sub2(c1.x, g1.x, d0[8],  d0[9]);  sub2(c1.y, g1.y, d0[10], d0[11]);
  sub2(c1.z, g1.z, d0[12], d0[13]); sub2(c1.w, g1.w, d0[14], d0[15]);
  sub2(c2.x, g2.x, d1[0],  d1[1]);  sub2(c2.y, g2.y, d1[2],  d1[3]);
  sub2(c2.z, g2.z, d1[4],  d1[5]);  sub2(c2.w, g2.w, d1[6],  d1[7]);
  sub2(c3.x, g3.x, d1[8],  d1[9]);  sub2(c3.y, g3.y, d1[10], d1[11]);
  sub2(c3.z, g3.z, d1[12], d1[13]); sub2(c3.w, g3.w, d1[14], d1[15]);

  float ex[16];
#pragma unroll
  for (int c = 0; c < 16; ++c) {
    const float x = d0[c] + d1[c];
    const float inc = wave_incl_scan(x);
    ex[c] = inc - x;
    if (lane == 63) wdTot[w][c] = inc;
  }
  __syncthreads();

  // wave 0: bsv[wt][c] = Th[c] + sum(G groups 4b-8..4b-1) + sum_{w'<wt} wdTot
  if (w == 0) {
    const int wt = lane & 7, cp = lane >> 3;   // channels 2cp, 2cp+1
    float b0 = 0.f, b1 = 0.f, e0 = 0.f, e1 = 0.f;
    const int gbase = 4*b - 8;
#pragma unroll
    for (int gg = 0; gg < 8; ++gg) {
      const int gi = gbase + gg;
      if (gi >= 0) {
        b0 += G[gi*16 + 2*cp];
        b1 += G[gi*16 + 2*cp + 1];
      }
    }
#pragma unroll
    for (int wp = 0; wp < 8; ++wp) {
      const bool pz = (wp < wt);
      float2 dt = *(const float2*)&wdTot[wp][2*cp];
      e0 += pz ? dt.x : 0.f;
      e1 += pz ? dt.y : 0.f;
    }
    const float2 th = *(const float2*)&g_Th[2*cp];
    *(float2*)&bsv[wt][2*cp] = make_float2(th.x + b0 + e0, th.y + b1 + e1);
  }
  __syncthreads();

  float bs[16];
#pragma unroll
  for (int q = 0; q < 4; ++q) {
    float4 t4 = *(const float4*)&bsv[w][4*q];
    bs[4*q] = t4.x; bs[4*q+1] = t4.y; bs[4*q+2] = t4.z; bs[4*q+3] = t4.w;
  }
  float wk[16];
#pragma unroll
  for (int k = 0; k < 16; ++k) wk[k] = rfl(g_W[k]);
  const float Vo = rfl(g_Vo);

  float W0v[16], W1v[16];
#pragma unroll
  for (int c = 0; c < 16; ++c) {
    W0v[c] = bs[c] + ex[c] + d0[c];
    W1v[c] = W0v[c] + d1[c];
  }
  float v0r = ftanh(W0v[15]);
  float v1r = ftanh(W1v[15]);
#pragma unroll
  for (int idx = 14; idx >= 0; --idx) {
    const float wkk = wk[idx + 1];
    v0r = ftanh(W0v[idx] + wkk * v0r);
    v1r = ftanh(W1v[idx] + wkk * v1r);
  }
  const float o0 = v0r * wk[0] + Vo;
  const float o1 = v1r * wk[0] + Vo;

  if (a0) {
    if (r0 + 1 < T) *(float2*)(out + r0) = make_float2(o0, o1);
    else            out[r0] = o0;
  }
}

extern "C" void kernel_launch(void* const* d_in, const int* in_sizes, int n_in,
                              void* d_out, int out_size, void* d_ws, size_t ws_size,
                              hipStream_t stream) {
  const float* S_e       = (const float*)d_in[0];
  const float* S_i       = (const float*)d_in[1];
  const float* alpha_log = (const float*)d_in[2];
  const float* beta      = (const float*)d_in[3];
  const float* gamma_log = (const float*)d_in[4];
  const float* kvlog     = (const float*)d_in[5];
  const float* mean_u    = (const float*)d_in[6];
  const float* su_low    = (const float*)d_in[7];
  const float* u_in      = (const float*)d_in[8];
  const float* W_log     = (const float*)d_in[9];
  const float* V_o       = (const float*)d_in[10];
  const float* Theta     = (const float*)d_in[11];
  (void)n_in; (void)out_size; (void)ws_size;

  const int T = in_sizes[0] / NSUB;
  const int nA = (T + GRP - 1) / GRP;    // k_fold blocks / G groups
  const int nB = (T + WR - 1) / WR;      // k_out blocks

  // d_ws layout: M (f16, T x 16 ch = 32 B/row) then G (nA x 16 f32)
  uint4* M4 = (uint4*)d_ws;
  float* G  = (float*)((char*)d_ws + (size_t)T * 32);

  hipLaunchKernelGGL(k_setup, dim3(32), dim3(64), 0, stream,
                     alpha_log, beta, gamma_log, kvlog, mean_u, su_low, u_in,
                     W_log, V_o, Theta, (float*)d_out, T);
  hipLaunchKernelGGL(k_fold, dim3(nA), dim3(512), 0, stream,
                     S_e, S_i, M4, G, T);
  hipLaunchKernelGGL(k_out, dim3(nB), dim3(512), 0, stream,
                     M4, G, (float*)d_out, T);
}

// Round 8
// 52.612 us; speedup vs baseline: 1.4978x; 1.3095x over previous
//
#include <hip/hip_runtime.h>
#include <hip/hip_fp16.h>

#define NSUB 16
#define MM 20
#define NFILT 2000
#define TRI (MM*(MM+1)/2)
#define GR 500           // rows per G group / k_fold block
#define WR 1000          // output rows per k_out block

// params published by setup kernel, consumed by later kernels (same-stream order)
__device__ __align__(16) float g_mu[32];
__device__ __align__(16) float g_W[16];
__device__ __align__(16) float g_Th[16];
__device__ float g_Vo;

__device__ __forceinline__ float ftanh(float x) {
  x = fminf(10.f, fmaxf(-10.f, x));
  float e = __expf(2.f * x);
  return (e - 1.f) * __builtin_amdgcn_rcpf(e + 1.f);
}

__device__ __forceinline__ float rfl(float v) {
  return __int_as_float(__builtin_amdgcn_readfirstlane(__float_as_int(v)));
}

__device__ __forceinline__ float f4c(const float4& v, int c) {
  return c == 0 ? v.x : c == 1 ? v.y : c == 2 ? v.z : v.w;
}

// full wave64 inclusive add-scan, pure VALU DPP (HW-validated R2)
__device__ __forceinline__ float wave_incl_scan(float x) {
  float t;
  t = __int_as_float(__builtin_amdgcn_update_dpp(0, __float_as_int(x), 0x111, 0xf, 0xf, true)); x += t;
  t = __int_as_float(__builtin_amdgcn_update_dpp(0, __float_as_int(x), 0x112, 0xf, 0xf, true)); x += t;
  t = __int_as_float(__builtin_amdgcn_update_dpp(0, __float_as_int(x), 0x114, 0xf, 0xf, true)); x += t;
  t = __int_as_float(__builtin_amdgcn_update_dpp(0, __float_as_int(x), 0x118, 0xf, 0xf, true)); x += t;
  t = __int_as_float(__builtin_amdgcn_update_dpp(0, __float_as_int(x), 0x142, 0xa, 0xf, true)); x += t; // bcast15
  t = __int_as_float(__builtin_amdgcn_update_dpp(0, __float_as_int(x), 0x143, 0xc, 0xf, true)); x += t; // bcast31
  return x;
}

// f16x2 helpers
__device__ __forceinline__ unsigned int f2h2(float a, float b) {
  __half2 h = __floats2half2_rn(a, b);
  union { __half2 h; unsigned int u; } cv; cv.h = h; return cv.u;
}
__device__ __forceinline__ void sub2(unsigned int cu, unsigned int lg, float& o0, float& o1) {
  union { unsigned int u; __half2 h; } a, b;
  a.u = cu; b.u = lg;
  float2 fa = __half22float2(a.h), fb = __half22float2(b.h);
  o0 = fa.x - fb.x; o1 = fa.y - fb.y;
}

// ---------------------------------------------------------------------------
// Setup: one 64-thread block per subunit; register-column Gauss-Jordan.
// (Validated R5-R7.)
// ---------------------------------------------------------------------------
__global__ void __launch_bounds__(64)
k_setup(const float* alpha_log, const float* beta_p, const float* gamma_log,
        const float* kvlog, const float* mean_u, const float* su_low,
        const float* u_in, const float* W_log, const float* V_o_p,
        const float* Theta, float* out, int T)
{
  const int s = blockIdx.x;       // 0..31
  const int lane = threadIdx.x;   // 0..63

  const float alpha = __expf(alpha_log[s]);
  const float beta  = beta_p[s];
  const float gamma = __expf(gamma_log[s]);
  const float kv    = __expf(kvlog[s]);
  const float fs    = (float)s;

  const long long OFF_MEANU = T;
  const long long OFF_SU    = (long long)T + 640;
  const long long OFF_COV   = (long long)T + 640 + 12800;
  const long long OFF_INV   = (long long)T + 640 + 2*12800;
  const long long OFF_FE    = (long long)T + 640 + 3*12800;
  const long long OFF_FI    = OFF_FE + 32000;
  const long long OFF_UIN   = OFF_FI + 32000;

  float urv[MM], t1v[MM], rv_[MM];
#pragma unroll
  for (int i = 0; i < MM; ++i) {
    float u = u_in[s*MM + i];
    urv[i] = u;
    t1v[i] = alpha * (u - beta) * (u - beta);
    rv_[i] = kv * __expf(-alpha*(fs-beta)*(fs-beta) - gamma*(fs-u)*(fs-u) - t1v[i]);
  }

  const bool cL = lane < MM;
  const bool cR = lane >= MM && lane < 2*MM;
  const float u_l = u_in[s*MM + (cL ? lane : 0)];
  const float t1_l = alpha * (u_l - beta) * (u_l - beta);

  float col[MM];
#pragma unroll
  for (int i = 0; i < MM; ++i) {
    float du = urv[i] - u_l;
    float cv = kv * __expf(-t1v[i] - gamma*du*du - t1_l);
    float idv = (lane - MM == i) ? 1.f : 0.f;
    col[i] = cL ? cv : (cR ? idv : 0.f);
    if (cL) out[OFF_COV + (long long)s*400 + i*MM + lane] = cv;
  }

#pragma unroll
  for (int k = 0; k < MM; ++k) {
    float fc[MM];
#pragma unroll
    for (int i = 0; i < MM; ++i)
      fc[i] = __int_as_float(__builtin_amdgcn_readlane(__float_as_int(col[i]), k));
    const float pr = 1.0f / fc[k];
    col[k] *= pr;
#pragma unroll
    for (int i = 0; i < MM; ++i)
      if (i != k) col[i] = fmaf(-fc[i], col[k], col[i]);
  }

  if (cR) {
    const int t = lane - MM;
#pragma unroll
    for (int i = 0; i < MM; ++i)
      out[OFF_INV + (long long)s*400 + i*MM + t] = col[i];
  }

  float dotr = 0.f;
#pragma unroll
  for (int i = 0; i < MM; ++i) dotr += rv_[i] * col[i];
  float mpart = cR ? dotr * mean_u[s*MM + (lane - MM)] : 0.f;
  float mu = mpart;
#pragma unroll
  for (int o = 1; o < 64; o <<= 1) mu += __shfl_xor(mu, o, 64);
  mu = rfl(mu);
  if (lane == 0) g_mu[s] = mu;

  __shared__ float Lm[MM][MM];
  for (int c = lane; c < MM*MM; c += 64) Lm[c/MM][c%MM] = 0.f;
  __syncthreads();
  for (int k = lane; k < TRI; k += 64) {
    int i = (int)((sqrtf(8.f*(float)k + 1.f) - 1.f) * 0.5f);
    while ((i+1)*(i+2)/2 <= k) ++i;
    while (i*(i+1)/2 > k) --i;
    int jx = k - i*(i+1)/2;
    Lm[i][jx] = su_low[s*TRI + k];
  }
  __syncthreads();
  for (int c = lane; c < MM*MM; c += 64) {
    int i = c / MM, kk = c % MM;
    float acc = 0.f;
#pragma unroll
    for (int jx = 0; jx < MM; ++jx) acc += Lm[i][jx] * Lm[kk][jx];
    out[OFF_SU + (long long)s*400 + c] = acc;
  }

  if (cL) {
    out[OFF_MEANU + s*MM + lane] = mean_u[s*MM + lane];
    out[OFF_UIN  + s*MM + lane] = u_l;
  }

  {
    long long base = (s < NSUB) ? (OFF_FE + (long long)s*NFILT)
                                : (OFF_FI + (long long)(s - NSUB)*NFILT);
    float2 f2 = make_float2(mu, mu);
    float2* dst = (float2*)(out + base);
    for (int n = lane; n < NFILT/2; n += 64) dst[n] = f2;
  }

  if (s == 0) {
    if (lane < 16) {
      g_W[lane]  = __expf(W_log[lane]);
      g_Th[lane] = Theta[lane];
    }
    if (lane == 0) g_Vo = V_o_p[0];
  }
}

// ---------------------------------------------------------------------------
// k_fold: pure stream, quarter-row per thread (100% dense loads AND stores).
// Block a covers rows [500a, 500a+500): 4 sweeps x 128 rows (last masked).
// Lane address = base*4 + lane for both float4 loads and uint2 stores.
// Tail: 16 shfl_xor (4ch x 4 steps) + tiny LDS for G[a][16].
// ---------------------------------------------------------------------------
__global__ void __launch_bounds__(512, 4)
k_fold(const float4* __restrict__ E4, const float4* __restrict__ I4,
       uint2* __restrict__ M2, float* __restrict__ G, int T)
{
  __shared__ float wsum[8][16];
  const int tid  = threadIdx.x;    // 0..511
  const int lane = tid & 63;
  const int w    = tid >> 6;       // 0..7
  const int g    = tid & 3;        // quarter: channels 4g..4g+3
  const int a    = blockIdx.x;

  const float4 mue4 = *(const float4*)&g_mu[4*g];
  const float4 mui4 = *(const float4*)&g_mu[16 + 4*g];
  const float4 z4 = make_float4(0.f, 0.f, 0.f, 0.f);

  float gsum[4] = {0.f, 0.f, 0.f, 0.f};

  float4 ebuf[4], ibuf[4];
#pragma unroll
  for (int sw = 0; sw < 4; ++sw) {
    const int rl = sw*128 + (tid >> 2);
    const long long r = (long long)a*GR + rl;
    const bool act = (rl < GR) && (r < T);
    const long long qi = r*4 + g;             // = base*4 + lane : dense
    ebuf[sw] = act ? E4[qi] : z4;
    ibuf[sw] = act ? I4[qi] : z4;
  }
#pragma unroll
  for (int sw = 0; sw < 4; ++sw) {
    const int rl = sw*128 + (tid >> 2);
    const long long r = (long long)a*GR + rl;
    const bool act = (rl < GR) && (r < T);
    float m[4];
#pragma unroll
    for (int c = 0; c < 4; ++c) {
      m[c] = f4c(mue4, c)*f4c(ebuf[sw], c) + f4c(mui4, c)*f4c(ibuf[sw], c);
      gsum[c] += m[c];
    }
    if (act) {
      uint2 pk;
      pk.x = f2h2(m[0], m[1]);
      pk.y = f2h2(m[2], m[3]);
      M2[r*4 + g] = pk;                       // dense uint2 store
    }
  }

  // per-block channel sums: lanes with equal (lane&3) hold same channels
#pragma unroll
  for (int c = 0; c < 4; ++c) {
#pragma unroll
    for (int o = 4; o <= 32; o <<= 1) gsum[c] += __shfl_xor(gsum[c], o, 64);
  }
  if (lane < 4)
    *(float4*)&wsum[w][4*lane] = make_float4(gsum[0], gsum[1], gsum[2], gsum[3]);
  __syncthreads();
  if (tid < 16) {
    float acc = 0.f;
#pragma unroll
    for (int wp = 0; wp < 8; ++wp) acc += wsum[wp][tid];
    G[a*16 + tid] = acc;
  }
}

// ---------------------------------------------------------------------------
// k_out: block b outputs rows [1000b, 1000b+1000); 1024 threads, 1 row/thread.
// W[t] = Th + sum(G over [s-2000,s)) + scan(M[s..t] - M[s-2000..t-2000]).
// 4 uint4 loads (50% density), per-channel DPP scan over 16 wave-segments,
// wave0 16x16 base table, one tanh chain/thread, dense f32 store.
// ---------------------------------------------------------------------------
__global__ void __launch_bounds__(1024, 2)
k_out(const uint4* __restrict__ M4, const float* __restrict__ G,
      float* __restrict__ out, int T)
{
  __shared__ float wdTot[16][16];
  __shared__ float bsv[16][16];
  const int tid  = threadIdx.x;    // 0..1023
  const int lane = tid & 63;
  const int w    = tid >> 6;       // 0..15
  const int b    = blockIdx.x;
  const long long s = (long long)b * WR;
  const long long r = s + tid;
  const bool act = (tid < WR) && (r < T);
  const long long l = r - NFILT;
  const bool vl = act && (l >= 0);

  const uint4 zu = make_uint4(0u, 0u, 0u, 0u);
  uint4 c0 = act ? M4[r*2]     : zu;
  uint4 c1 = act ? M4[r*2 + 1] : zu;
  uint4 g0 = vl  ? M4[l*2]     : zu;
  uint4 g1 = vl  ? M4[l*2 + 1] : zu;

  float d[16];
  sub2(c0.x, g0.x, d[0],  d[1]);  sub2(c0.y, g0.y, d[2],  d[3]);
  sub2(c0.z, g0.z, d[4],  d[5]);  sub2(c0.w, g0.w, d[6],  d[7]);
  sub2(c1.x, g1.x, d[8],  d[9]);  sub2(c1.y, g1.y, d[10], d[11]);
  sub2(c1.z, g1.z, d[12], d[13]); sub2(c1.w, g1.w, d[14], d[15]);

  float inc[16];
#pragma unroll
  for (int c = 0; c < 16; ++c) {
    inc[c] = wave_incl_scan(d[c]);
    if (lane == 63) wdTot[w][c] = inc[c];
  }
  __syncthreads();

  // wave 0: bsv[wt][4q..4q+3] = Th + sum(G[2b-4..2b-1]) + sum_{w'<wt} wdTot
  if (w == 0) {
    const int wt = lane & 15, q = lane >> 4;   // channels 4q..4q+3
    float4 acc = *(const float4*)&g_Th[4*q];
#pragma unroll
    for (int gg = 0; gg < 4; ++gg) {
      const int gi = 2*b - 4 + gg;
      if (gi >= 0) {
        float4 gv = *(const float4*)&G[gi*16 + 4*q];
        acc.x += gv.x; acc.y += gv.y; acc.z += gv.z; acc.w += gv.w;
      }
    }
#pragma unroll
    for (int wp = 0; wp < 16; ++wp) {
      if (wp < wt) {
        float4 dv = *(const float4*)&wdTot[wp][4*q];
        acc.x += dv.x; acc.y += dv.y; acc.z += dv.z; acc.w += dv.w;
      }
    }
    *(float4*)&bsv[wt][4*q] = acc;
  }
  __syncthreads();

  float Wv[16];
#pragma unroll
  for (int q = 0; q < 4; ++q) {
    float4 t4 = *(const float4*)&bsv[w][4*q];
    Wv[4*q]   = t4.x + inc[4*q];
    Wv[4*q+1] = t4.y + inc[4*q+1];
    Wv[4*q+2] = t4.z + inc[4*q+2];
    Wv[4*q+3] = t4.w + inc[4*q+3];
  }
  float wk[16];
#pragma unroll
  for (int k = 0; k < 16; ++k) wk[k] = rfl(g_W[k]);
  const float Vo = rfl(g_Vo);

  float v = ftanh(Wv[15]);
#pragma unroll
  for (int idx = 14; idx >= 0; --idx)
    v = ftanh(Wv[idx] + wk[idx + 1] * v);

  if (act) out[r] = v * wk[0] + Vo;
}

extern "C" void kernel_launch(void* const* d_in, const int* in_sizes, int n_in,
                              void* d_out, int out_size, void* d_ws, size_t ws_size,
                              hipStream_t stream) {
  const float* S_e       = (const float*)d_in[0];
  const float* S_i       = (const float*)d_in[1];
  const float* alpha_log = (const float*)d_in[2];
  const float* beta      = (const float*)d_in[3];
  const float* gamma_log = (const float*)d_in[4];
  const float* kvlog     = (const float*)d_in[5];
  const float* mean_u    = (const float*)d_in[6];
  const float* su_low    = (const float*)d_in[7];
  const float* u_in      = (const float*)d_in[8];
  const float* W_log     = (const float*)d_in[9];
  const float* V_o       = (const float*)d_in[10];
  const float* Theta     = (const float*)d_in[11];
  (void)n_in; (void)out_size; (void)ws_size;

  const int T = in_sizes[0] / NSUB;
  const int nG = (T + GR - 1) / GR;      // k_fold blocks / G groups
  const int nB = (T + WR - 1) / WR;      // k_out blocks

  // d_ws layout: M (f16, T x 16 ch = 32 B/row) then G (nG x 16 f32)
  uint2* M2 = (uint2*)d_ws;
  float* G  = (float*)((char*)d_ws + (size_t)T * 32);

  hipLaunchKernelGGL(k_setup, dim3(32), dim3(64), 0, stream,
                     alpha_log, beta, gamma_log, kvlog, mean_u, su_low, u_in,
                     W_log, V_o, Theta, (float*)d_out, T);
  hipLaunchKernelGGL(k_fold, dim3(nG), dim3(512), 0, stream,
                     (const float4*)S_e, (const float4*)S_i, M2, G, T);
  hipLaunchKernelGGL(k_out, dim3(nB), dim3(1024), 0, stream,
                     (const uint4*)M2, G, (float*)d_out, T);
}